// Round 10
// baseline (270.566 us; speedup 1.0000x reference)
//
#include <hip/hip_runtime.h>
#include <hip/hip_bf16.h>

typedef __bf16 bf16;
typedef __bf16 bf16x8 __attribute__((ext_vector_type(8)));
typedef __bf16 bf16x4 __attribute__((ext_vector_type(4)));
typedef __bf16 bf16x2 __attribute__((ext_vector_type(2)));
typedef float f32x4 __attribute__((ext_vector_type(4)));
typedef float f32x16 __attribute__((ext_vector_type(16)));

static __device__ __forceinline__ f32x4 mfma16(bf16x8 a, bf16x8 b, f32x4 c) {
    return __builtin_amdgcn_mfma_f32_16x16x32_bf16(a, b, c, 0, 0, 0);
}
static __device__ __forceinline__ f32x16 mfma32(bf16x8 a, bf16x8 b, f32x16 c) {
    return __builtin_amdgcn_mfma_f32_32x32x16_bf16(a, b, c, 0, 0, 0);
}

static __device__ __forceinline__ void load16_to_lds(const void* g, void* l) {
    __builtin_amdgcn_global_load_lds(
        (const __attribute__((address_space(1))) unsigned int*)g,
        (__attribute__((address_space(3))) unsigned int*)l, 16, 0, 0);
}

#define LKV 2048
#define DM 256

// ================= shared GEMM body: Y[64 x 256] = X * W^T, W read as f32 =================
template<bool IN_BF16, bool OUT_BF16, bool HAS_BIAS>
static __device__ __forceinline__ void gemm_body(char* smem,
                                                 const void* __restrict__ Xv,
                                                 const float* __restrict__ Wf,
                                                 const float* __restrict__ bias,
                                                 float scale, void* __restrict__ Y,
                                                 long rowbase) {
    bf16* Xl  = (bf16*)smem;            // [64][264] bf16 (528B rows)
    char* WlB = smem + 33792;           // [256][40] bf16 (80B rows)
    const int tid  = threadIdx.x;
    const int lane = tid & 63, wave = tid >> 6;
    const int hi = lane >> 4, lo = lane & 15;

    if (IN_BF16) {
        const bf16* Xb = (const bf16*)Xv;
#pragma unroll
        for (int i = 0; i < 8; ++i) {
            int idx = i * 256 + tid;
            int r = idx >> 5, c8 = (idx & 31) * 8;
            uint4 v = *(const uint4*)(Xb + (rowbase + r) * 256 + c8);
            *(uint4*)(Xl + r * 264 + c8) = v;
        }
    } else {
        const float* X = (const float*)Xv;
#pragma unroll
        for (int i = 0; i < 16; ++i) {
            int idx4 = i * 256 + tid;
            int e = idx4 * 4;
            int r = e >> 8, c = e & 255;
            float4 v = *(const float4*)(X + (rowbase + r) * 256 + c);
            bf16x4 o;
            o[0] = (bf16)v.x; o[1] = (bf16)v.y; o[2] = (bf16)v.z; o[3] = (bf16)v.w;
            *(bf16x4*)(Xl + r * 264 + c) = o;
        }
    }

    f32x4 acc[16];
    const f32x4 zero = {0.f, 0.f, 0.f, 0.f};
#pragma unroll
    for (int n = 0; n < 16; ++n) acc[n] = zero;

    for (int ks = 0; ks < 8; ++ks) {
        __syncthreads();
#pragma unroll
        for (int c = 0; c < 8; ++c) {
            int idx = c * 256 + tid;            // 2048 float4 chunks
            int e = idx >> 3, q4 = (idx & 7) * 4;
            float4 v = *(const float4*)(Wf + e * 256 + ks * 32 + q4);
            bf16x4 o;
            o[0] = (bf16)v.x; o[1] = (bf16)v.y; o[2] = (bf16)v.z; o[3] = (bf16)v.w;
            *(bf16x4*)(WlB + e * 80 + q4 * 2) = o;
        }
        __syncthreads();
        bf16x8 a = *(const bf16x8*)((const char*)Xl + (wave * 16 + lo) * 528 + ks * 64 + hi * 16);
#pragma unroll
        for (int n = 0; n < 16; ++n) {
            bf16x8 bfr = *(const bf16x8*)(WlB + (n * 16 + lo) * 80 + hi * 16);
            acc[n] = mfma16(a, bfr, acc[n]);
        }
    }

#pragma unroll
    for (int n = 0; n < 16; ++n) {
        int col = n * 16 + lo;
        float bv = HAS_BIAS ? bias[col] : 0.f;
#pragma unroll
        for (int r = 0; r < 4; ++r) {
            long row = rowbase + wave * 16 + hi * 4 + r;
            float v = acc[n][r] * scale + bv;
            if (OUT_BF16) ((bf16*)Y)[row * 256 + col] = (bf16)v;
            else          ((float*)Y)[row * 256 + col] = v;
        }
    }
}

// ================= prep_qk: blocks [0,1024) = q/k projection; [1024,3072) = tsp -> tspF ======
// tspF frag layout: byte addr = b*1MB + ((t32*16 + dt)*64 + fl)*16,
// holding tspT[d = dt*16 + (fl&15)][kv = t32*32 + (fl>>4)*8 .. +7] as bf16x8.
__global__ __launch_bounds__(256) void prep_qk(const float* __restrict__ q,
                                               const float* __restrict__ k,
                                               const float* __restrict__ wqk,
                                               const float* __restrict__ tsp,
                                               bf16* __restrict__ qp,
                                               bf16* __restrict__ kp,
                                               bf16* __restrict__ tspF) {
    __shared__ __align__(16) char smem[54272];
    const int tid = threadIdx.x;
    int bid = (int)blockIdx.x;
    if (bid < 1024) {
        bool is_k = bid >= 512;
        // qp scale folds 1/temperature (1/16) AND log2e (exp2-based softmax)
        gemm_body<false, true, false>(smem, is_k ? k : q, wqk, nullptr,
                                      is_k ? 1.0f : 0.09016844f, is_k ? kp : qp,
                                      (long)(bid & 511) * 64);
        return;
    }
    int id = bid - 1024;                       // 2048 tiles: 16 b x 32 kv-tiles x 4 d-tiles
    const int b = id >> 7;
    const int kv0 = (id & 31) * 64, d0 = ((id >> 5) & 3) * 64;
    float (*tile)[65] = (float(*)[65])smem;
#pragma unroll
    for (int i = 0; i < 4; ++i) {
        int idx = i * 256 + tid;
        int kv = idx >> 4, c4 = (idx & 15) * 4;
        float4 v = *(const float4*)(tsp + ((long)(b * LKV + kv0 + kv)) * DM + d0 + c4);
        tile[kv][c4 + 0] = v.x; tile[kv][c4 + 1] = v.y;
        tile[kv][c4 + 2] = v.z; tile[kv][c4 + 3] = v.w;
    }
    __syncthreads();
    char* outb = (char*)tspF + ((long)b << 20);
#pragma unroll
    for (int i = 0; i < 2; ++i) {
        int w = i * 256 + tid;
        int ti = w >> 8;
        int dti = (w >> 6) & 3;
        int fl = w & 63;
        int hi = fl >> 4, lo = fl & 15;
        bf16x8 o;
#pragma unroll
        for (int j = 0; j < 8; ++j) o[j] = (bf16)tile[ti * 32 + hi * 8 + j][dti * 16 + lo];
        int t_abs = (kv0 >> 5) + ti;
        int dt_abs = (d0 >> 4) + dti;
        *(bf16x8*)(outb + (((t_abs * 16 + dt_abs) << 6) + fl) * 16) = o;
    }
}

// ================= gemm_out ==================================================================
__global__ __launch_bounds__(256) void gemm_out(const bf16* __restrict__ gated,
                                                const float* __restrict__ w1,
                                                const float* __restrict__ b1,
                                                float* __restrict__ out) {
    __shared__ __align__(16) char smem[54272];
    gemm_body<true, false, true>(smem, gated, w1, b1, 1.0f, out, (long)blockIdx.x * 64);
}

// ================= flash v9: 32x32 MFMA, 8 waves = 4 q-groups x 2 kv-halves ==================
// grid = 256 (1 block/CU, XCD-swizzled), block = 512. Each wave: 32 q-rows, 1024 kv, 32 phases.
// kp per half double-buffered in LDS (row-major 512B rows, kv&7 swizzle); tsp frags global->reg.
// S^T = mfma32(K, Q): lane q-col = lane&31, 16 kv-rows = (reg&3)+8*(reg>>2)+4*(lane>>5).
// P exchange to B-frag via 8x shfl_xor(32). kv-halves merge in LDS at the end.
__global__ __launch_bounds__(512, 2) void flash9(const bf16* __restrict__ qp,
                                                 const bf16* __restrict__ kp,
                                                 const bf16* __restrict__ tspF,
                                                 const float* __restrict__ qorig,
                                                 bf16* __restrict__ gated) {
    __shared__ __align__(16) char smem[67072];   // [0,64K): kbuf 2 halves x 2 slots x 16K
                                                 // merge reuses [0,64K); lmt at +65536 (1.5K)
    const int tid  = threadIdx.x;
    const int lane = tid & 63, wave = tid >> 6;
    const int half = wave >> 2, w4 = wave & 3;
    const int l31 = lane & 31, hi32 = lane >> 5;

    int id  = (int)blockIdx.x;
    int bid = (id & 7) * 32 + (id >> 3);         // 8 XCDs x 32 blocks -> 2 batches/XCD
    const int b  = bid >> 4;
    const int qb = bid & 15;
    const long qbase = (long)b * LKV + qb * 128;
    const char* kp_g  = (const char*)(kp + (long)b * LKV * DM) + half * 524288;
    const char* tsp_f = (const char*)tspF + ((long)b << 20);
    char* kbase = smem + half * 32768;

    int kp_off[4];
#pragma unroll
    for (int j = 0; j < 4; ++j) {
        int kv = w4 * 8 + j * 2 + (lane >> 5);
        kp_off[j] = kv * 512 + (((lane & 31) ^ (kv & 7)) << 4);
    }
    const int kswz = (l31 & 7) << 4;
    const int tfo0 = ((l31 >> 4) << 10) + ((l31 & 15) << 4) + (hi32 << 8);

    // Q B-frags: q-col = l31, k = ki*16 + hi32*8 + j
    bf16x8 aq[16];
    {
        const bf16* qrow = qp + (qbase + w4 * 32 + l31) * DM;
#pragma unroll
        for (int ki = 0; ki < 16; ++ki)
            aq[ki] = *(const bf16x8*)(qrow + ki * 16 + hi32 * 8);
    }

    const f32x16 z16 = {0.f,0.f,0.f,0.f,0.f,0.f,0.f,0.f,0.f,0.f,0.f,0.f,0.f,0.f,0.f,0.f};
    f32x16 o[8];
#pragma unroll
    for (int n = 0; n < 8; ++n) o[n] = z16;
    float l_own = 0.f, m = -1e30f, tm = -1e30f;

    // prologue: DMA kp tiles 0,1 of this half into slots 0,1
#pragma unroll
    for (int j = 0; j < 4; ++j)
        load16_to_lds(kp_g + kp_off[j],          kbase + w4 * 4096 + j * 1024);
#pragma unroll
    for (int j = 0; j < 4; ++j)
        load16_to_lds(kp_g + 16384 + kp_off[j],  kbase + 16384 + w4 * 4096 + j * 1024);

    for (int t = 0; t < 32; ++t) {
        if (t < 31) { asm volatile("s_waitcnt vmcnt(4)" ::: "memory"); }
        else        { asm volatile("s_waitcnt vmcnt(0)" ::: "memory"); }
        __builtin_amdgcn_sched_barrier(0);
        __builtin_amdgcn_s_barrier();
        __builtin_amdgcn_sched_barrier(0);

        const char* ttb = tsp_f + (long)(half * 32 + t) * 16384;
        bf16x8 tt[3][2];
        tt[0][0] = *(const bf16x8*)(ttb + tfo0);
        tt[0][1] = *(const bf16x8*)(ttb + tfo0 + 512);
        tt[1][0] = *(const bf16x8*)(ttb + 2048 + tfo0);
        tt[1][1] = *(const bf16x8*)(ttb + 2048 + tfo0 + 512);

        // ---- QK(t): S^T[kv32][q32] = sum_ki mfma32(K_frag, Q_frag) ----
        f32x16 s = z16;
        const char* kb = kbase + (t & 1) * 16384;
        __builtin_amdgcn_s_setprio(1);
#pragma unroll
        for (int ki = 0; ki < 16; ++ki) {
            bf16x8 kk = *(const bf16x8*)(kb + l31 * 512 + ((ki * 32 + hi32 * 16) ^ kswz));
            s = mfma32(kk, aq[ki], s);
        }
        __builtin_amdgcn_s_setprio(0);

        __builtin_amdgcn_sched_barrier(0);
        __builtin_amdgcn_s_barrier();     // all waves done reading slot t&1
        __builtin_amdgcn_sched_barrier(0);

        // ---- softmax(t): lane has 16 kv for q=l31; partner (lane^32) has the other 16 ----
        float pm = s[0];
#pragma unroll
        for (int r = 1; r < 16; ++r) pm = fmaxf(pm, s[r]);
        pm = fmaxf(pm, __shfl_xor(pm, 32));
        tm = fmaxf(tm, pm);
        if (__any(pm > m + 11.5f)) {      // defer-max: 8 nats = 11.5 bits
            float nm = fmaxf(m, pm);
            float a = exp2f(m - nm);
            m = nm;
            l_own *= a;
#pragma unroll
            for (int n = 0; n < 8; ++n) o[n] *= a;
        }
        float p[16];
        float ls = 0.f;
#pragma unroll
        for (int r = 0; r < 16; ++r) { p[r] = exp2f(s[r] - m); ls += p[r]; }
        l_own += ls;

        // pack pairs; w[i] holds kv_loc {(2i..2i+1 pattern) + 4*hi32}
        int w[8];
#pragma unroll
        for (int i = 0; i < 8; ++i) {
            bf16x2 pr; pr[0] = (bf16)p[2 * i]; pr[1] = (bf16)p[2 * i + 1];
            w[i] = __builtin_bit_cast(int, pr);
        }
        int x0 = __shfl_xor(w[0], 32), x1 = __shfl_xor(w[1], 32);
        int x2 = __shfl_xor(w[2], 32), x3 = __shfl_xor(w[3], 32);
        int x4 = __shfl_xor(w[4], 32), x5 = __shfl_xor(w[5], 32);
        int x6 = __shfl_xor(w[6], 32), x7 = __shfl_xor(w[7], 32);
        int4 f0i, f1i;
        if (hi32 == 0) { f0i = make_int4(w[0], w[1], x0, x1); f1i = make_int4(w[4], w[5], x4, x5); }
        else           { f0i = make_int4(x2, x3, w[2], w[3]); f1i = make_int4(x6, x7, w[6], w[7]); }
        bf16x8 pf0 = __builtin_bit_cast(bf16x8, f0i);   // B-frag k-chunk 0 (kv 0-15)
        bf16x8 pf1 = __builtin_bit_cast(bf16x8, f1i);   // B-frag k-chunk 1 (kv 16-31)

        // ---- PV(t): O^T[d][q] += tsp_frag x P_frag; tsp frags streamed 3-deep ----
        __builtin_amdgcn_s_setprio(1);
#pragma unroll
        for (int db = 0; db < 8; ++db) {
            if (db < 6) {
                const char* t2 = ttb + (db + 2) * 2048;
                tt[(db + 2) % 3][0] = *(const bf16x8*)(t2 + tfo0);
                tt[(db + 2) % 3][1] = *(const bf16x8*)(t2 + tfo0 + 512);
            }
            o[db] = mfma32(tt[db % 3][0], pf0, o[db]);
            o[db] = mfma32(tt[db % 3][1], pf1, o[db]);
        }
        __builtin_amdgcn_s_setprio(0);

        // ---- DMA(t+2) into slot t&1 (after PV's tt drains -> loads span full next phase) ----
        if (t < 30) {
            const char* src = kp_g + (long)(t + 2) * 16384;
            char* dst = kbase + (t & 1) * 16384 + w4 * 4096;
#pragma unroll
            for (int j = 0; j < 4; ++j)
                load16_to_lds(src + kp_off[j], dst + j * 1024);
        }
    }

    // ================= merge kv-halves in LDS, epilogue by half 0 =================
    __syncthreads();
    float l2 = l_own + __shfl_xor(l_own, 32);
    float* lmt = (float*)(smem + 65536);
    if (half == 1 && hi32 == 0) {
        int qi = w4 * 32 + l31;
        lmt[qi * 3 + 0] = l2; lmt[qi * 3 + 1] = m; lmt[qi * 3 + 2] = tm;
    }
    float aA = 1.f, aB = 0.f, invl = 0.f, prob = 0.f;
    long row = qbase + w4 * 32 + l31;
#pragma unroll
    for (int round = 0; round < 2; ++round) {
        __syncthreads();
        if (half == 1) {
#pragma unroll
            for (int db = 0; db < 4; ++db) {
                float* dst = (float*)smem + (w4 * 4 + db) * 1024 + lane * 16;
                f32x16 v = o[round * 4 + db];
#pragma unroll
                for (int c = 0; c < 4; ++c) {
                    float4 f4;
                    f4.x = v[c * 4 + 0]; f4.y = v[c * 4 + 1];
                    f4.z = v[c * 4 + 2]; f4.w = v[c * 4 + 3];
                    *(float4*)(dst + c * 4) = f4;
                }
            }
        }
        __syncthreads();
        if (half == 0) {
            if (round == 0) {
                int qi = w4 * 32 + l31;
                float lB = lmt[qi * 3 + 0], mB = lmt[qi * 3 + 1], tmB = lmt[qi * 3 + 2];
                float M = fmaxf(m, mB);
                aA = exp2f(m - M); aB = exp2f(mB - M);
                invl = 1.f / (l2 * aA + lB * aB);
                float tmM = fmaxf(tm, tmB);
                prob = 1.f / (1.f + __expf(-tmM * 0.69314718f));
            }
#pragma unroll
            for (int db = 0; db < 4; ++db) {
                const float* srcp = (const float*)smem + (w4 * 4 + db) * 1024 + lane * 16;
                f32x16 oc = o[round * 4 + db];
                int d0 = (round * 4 + db) * 32;
#pragma unroll
                for (int g2 = 0; g2 < 4; ++g2) {
                    float4 ob = *(const float4*)(srcp + g2 * 4);
                    int d = d0 + g2 * 8 + hi32 * 4;
                    float4 qv = *(const float4*)(qorig + row * 256 + d);
                    bf16x4 gg;
                    gg[0] = (bf16)((qv.x + (oc[g2 * 4 + 0] * aA + ob.x * aB) * invl) * prob);
                    gg[1] = (bf16)((qv.y + (oc[g2 * 4 + 1] * aA + ob.y * aB) * invl) * prob);
                    gg[2] = (bf16)((qv.z + (oc[g2 * 4 + 2] * aA + ob.z * aB) * invl) * prob);
                    gg[3] = (bf16)((qv.w + (oc[g2 * 4 + 3] * aA + ob.w * aB) * invl) * prob);
                    *(bf16x4*)(gated + row * 256 + d) = gg;
                }
            }
        }
    }
}

extern "C" void kernel_launch(void* const* d_in, const int* in_sizes, int n_in,
                              void* d_out, int out_size, void* d_ws, size_t ws_size,
                              hipStream_t stream) {
    const float* q    = (const float*)d_in[0];
    const float* k    = (const float*)d_in[1];
    const float* tsp  = (const float*)d_in[2];
    const float* w_qk = (const float*)d_in[3];
    const float* w1   = (const float*)d_in[4];
    const float* b1   = (const float*)d_in[5];
    float* out = (float*)d_out;
    char* ws = (char*)d_ws;

    bf16* qp_b  = (bf16*)(ws + 0);           // 16 MB
    bf16* kp_b  = (bf16*)(ws + 16777216);    // 16 MB
    bf16* tspF  = (bf16*)(ws + 33554432);    // 16 MB (frag layout)
    bf16* gated = (bf16*)(ws + 50331648);    // 16 MB

    prep_qk<<<3072, 256, 0, stream>>>(q, k, w_qk, tsp, qp_b, kp_b, tspF);

    flash9<<<256, 512, 0, stream>>>(qp_b, kp_b, tspF, q, gated);

    gemm_out<<<512, 256, 0, stream>>>(gated, w1, b1, out);
}